// Round 8
// baseline (420.489 us; speedup 1.0000x reference)
//
#include <hip/hip_runtime.h>

// ---------------- constants ----------------
#define TT 1000
#define BB 2
#define DD 768
#define HH 12
#define DK 64
#define LL 2
#define WELEM 589824          // 768*768
#define PEROWS 255            // rel positions -127..127
#define VTP 1312              // t-stride in vT layout (with 128 margin both sides)
#define PPL 195840            // per-layer pp elems: HH*PEROWS*DK

typedef __bf16 bf16x8 __attribute__((ext_vector_type(8)));
typedef float floatx4 __attribute__((ext_vector_type(4)));

__device__ __constant__ int HALFW[12] = {3,7,15,31,63,127,3,7,15,31,63,127};
__device__ __constant__ int HORD[12]  = {5,11,4,10,3,9,2,8,1,7,0,6};   // heavy bands first

// ---------------- helpers ----------------
__device__ __forceinline__ float b2f(unsigned short u){
    union { unsigned int i; float f; } x; x.i = ((unsigned int)u) << 16; return x.f;
}
__device__ __forceinline__ unsigned short f2b(float f){
    union { float f; unsigned int i; } x; x.f = f;
    unsigned int i = x.i;
    i += 0x7fffu + ((i >> 16) & 1u);   // RNE
    return (unsigned short)(i >> 16);
}
// async global->LDS, 16B per lane; lds dest is wave-uniform base + lane*16
__device__ __forceinline__ void gload16(const void* g, void* l){
    __builtin_amdgcn_global_load_lds(
        (const __attribute__((address_space(1))) void*)g,
        (__attribute__((address_space(3))) void*)l, 16, 0, 0);
}

// ---------------- merged preamble: z<14 wconv slice; z=14 x-scale + layer0-ln1; z=15 pe ----------------
__global__ __launch_bounds__(256)
void prep_kernel(const float* s0, const float* s1, const float* s2, const float* s3,
                 const float* s4, const float* s5, const float* s6,
                 unsigned short* __restrict__ dst,
                 const float* __restrict__ x, float* __restrict__ xc,
                 unsigned short* __restrict__ pe,
                 const float* __restrict__ lg0, const float* __restrict__ lb0,
                 unsigned short* __restrict__ ln0out){
    int z = blockIdx.z;
    int tid = threadIdx.x;
    if (z < 14){
        const float* srcs[7] = {s0,s1,s2,s3,s4,s5,s6};
        const float* src = srcs[z % 7] + (size_t)(z / 7)*WELEM;
        unsigned short* d = dst + (size_t)z*WELEM;
        int k0 = blockIdx.x*64, n0 = blockIdx.y*64;
        __shared__ __align__(16) unsigned short tile[64][72];
        int r = tid >> 2, c = tid & 3;
        const float4* sp = (const float4*)(src + (size_t)(k0+r)*DD + n0 + c*16);
        float4 f0 = sp[0], f1 = sp[1], f2 = sp[2], f3 = sp[3];
        unsigned short u[16];
        u[0]=f2b(f0.x); u[1]=f2b(f0.y); u[2]=f2b(f0.z); u[3]=f2b(f0.w);
        u[4]=f2b(f1.x); u[5]=f2b(f1.y); u[6]=f2b(f1.z); u[7]=f2b(f1.w);
        u[8]=f2b(f2.x); u[9]=f2b(f2.y); u[10]=f2b(f2.z); u[11]=f2b(f2.w);
        u[12]=f2b(f3.x); u[13]=f2b(f3.y); u[14]=f2b(f3.z); u[15]=f2b(f3.w);
        *(int4*)&tile[r][c*16]   = *(int4*)&u[0];
        *(int4*)&tile[r][c*16+8] = *(int4*)&u[8];
        __syncthreads();
        unsigned short tmp[16];
        #pragma unroll
        for (int i=0;i<16;++i) tmp[i] = tile[c*16+i][r];
        int4* dp = (int4*)(d + (size_t)(n0+r)*DD + k0 + c*16);
        dp[0] = *(int4*)&tmp[0];
        dp[1] = *(int4*)&tmp[8];
    } else if (z == 14){
        // x-scale + layer-0 ln1 fused: wave-per-row, 14 rows per block instance
        int bid = blockIdx.y*12 + blockIdx.x;         // 0..143
        int wv = tid>>6, lane = tid&63;
        const float SCL = 27.712812921102035f;
        #pragma unroll
        for (int it = 0; it < 4; ++it){
            int rr = it*4 + wv;                       // 0..15
            if (rr < 14){
                int row = bid*14 + rr;
                if (row < 2000){
                    const float4* xr = (const float4*)x + (size_t)row*192;
                    float4* xcr = (float4*)xc + (size_t)row*192;
                    float4 vv[3];
                    float s = 0.f, ss = 0.f;
                    #pragma unroll
                    for (int j=0;j<3;++j){
                        float4 vq = xr[lane + 64*j];
                        vq.x *= SCL; vq.y *= SCL; vq.z *= SCL; vq.w *= SCL;
                        vv[j] = vq;
                        s  += vq.x+vq.y+vq.z+vq.w;
                        ss += vq.x*vq.x+vq.y*vq.y+vq.z*vq.z+vq.w*vq.w;
                        xcr[lane + 64*j] = vq;
                    }
                    #pragma unroll
                    for (int o=1;o<64;o<<=1){ s += __shfl_xor(s,o); ss += __shfl_xor(ss,o); }
                    float mean = s*(1.0f/768.0f);
                    float var  = ss*(1.0f/768.0f) - mean*mean;
                    float inv  = 1.0f/sqrtf(var + 1e-5f);
                    unsigned short* orow = ln0out + (size_t)row*768;
                    #pragma unroll
                    for (int j=0;j<3;++j){
                        int i0 = (lane + 64*j)*4;
                        unsigned short o4[4];
                        o4[0] = f2b((vv[j].x-mean)*inv*lg0[i0]   + lb0[i0]);
                        o4[1] = f2b((vv[j].y-mean)*inv*lg0[i0+1] + lb0[i0+1]);
                        o4[2] = f2b((vv[j].z-mean)*inv*lg0[i0+2] + lb0[i0+2]);
                        o4[3] = f2b((vv[j].w-mean)*inv*lg0[i0+3] + lb0[i0+3]);
                        *(unsigned long long*)&orow[i0] = *(unsigned long long*)o4;
                    }
                }
            }
        }
    } else {
        int bid = blockIdx.y*12 + blockIdx.x;         // 0..143
        #pragma unroll
        for (int rr = 0; rr < 2; ++rr){
            int row = bid*2 + rr;
            if (row < PEROWS){
                float pos = (float)(127 - row);
                int i = tid;
                float dv = expf((float)(2*i) * (-9.210340371976184f / 768.0f));
                float ang = pos * dv;
                pe[(size_t)row*DD + 2*i]   = f2b(sinf(ang));
                pe[(size_t)row*DD + 2*i+1] = f2b(cosf(ang));
                if (tid < 128){
                    int j = 256 + tid;
                    float dv2 = expf((float)(2*j) * (-9.210340371976184f / 768.0f));
                    float an2 = pos * dv2;
                    pe[(size_t)row*DD + 2*j]   = f2b(sinf(an2));
                    pe[(size_t)row*DD + 2*j+1] = f2b(cosf(an2));
                }
            }
        }
    }
}

// ======== GEMM core 64x64, 2-buffer, counted vmcnt (round-6 verified) ========
// sh must be: __shared__ __align__(16) unsigned short sh[16384];
#define GEMM_GL64(A_, Bt_, M0_, n0_, M_)                                        \
    int tid = threadIdx.x;                                                      \
    int m0 = (M0_);                                                             \
    int wv = tid>>6, lane = tid&63;                                             \
    int quad = lane>>4, l16 = lane&15;                                          \
    floatx4 acc[4];                                                             \
    _Pragma("unroll")                                                           \
    for (int ni=0;ni<4;++ni) acc[ni] = (floatx4){0.f,0.f,0.f,0.f};              \
    {                                                                           \
      int rl0 = wv*16 + (lane>>3);                                              \
      int rl1 = rl0 + 8;                                                        \
      int gc  = (lane&7) ^ (lane>>3);                                           \
      int ra0 = m0 + rl0; if (ra0 > (M_)-1) ra0 = (M_)-1;                       \
      int ra1 = m0 + rl1; if (ra1 > (M_)-1) ra1 = (M_)-1;                       \
      const char* gA0 = (const char*)(A_)  + (size_t)ra0*1536 + gc*16;          \
      const char* gA1 = (const char*)(A_)  + (size_t)ra1*1536 + gc*16;          \
      const char* gB0 = (const char*)(Bt_) + (size_t)((n0_)+rl0)*1536 + gc*16;  \
      const char* gB1 = (const char*)(Bt_) + (size_t)((n0_)+rl1)*1536 + gc*16;  \
      char* shB = (char*)sh;                                                    \
      int ld0 = (2*wv)*1024, ld1 = (2*wv+1)*1024;                               \
      int arow = (16*wv + l16)*64;                                              \
      int sw8  = l16 & 7;                                                       \
      int cq0 = (quad ^ sw8)*8;                                                 \
      int cq1 = ((4|quad) ^ sw8)*8;                                             \
      gload16(gA0, shB + ld0);                                                  \
      gload16(gA1, shB + ld1);                                                  \
      gload16(gB0, shB + 8192 + ld0);                                           \
      gload16(gB1, shB + 8192 + ld1);                                           \
      for (int s=0; s<12; ++s){                                                 \
        if (s < 11){                                                            \
          char* nb = shB + ((s+1)&1)*16384;                                     \
          int off = (s+1)*128;                                                  \
          gload16(gA0 + off, nb + ld0);                                         \
          gload16(gA1 + off, nb + ld1);                                         \
          gload16(gB0 + off, nb + 8192 + ld0);                                  \
          gload16(gB1 + off, nb + 8192 + ld1);                                  \
          asm volatile("s_waitcnt vmcnt(4)" ::: "memory");                      \
        } else {                                                                \
          asm volatile("s_waitcnt vmcnt(0)" ::: "memory");                      \
        }                                                                       \
        __builtin_amdgcn_s_barrier();                                           \
        __builtin_amdgcn_sched_barrier(0);                                      \
        const unsigned short* cA = sh + (s&1)*8192;                             \
        const unsigned short* cB = cA + 4096;                                   \
        _Pragma("unroll")                                                       \
        for (int kh=0; kh<2; ++kh){                                             \
          int cq = kh ? cq1 : cq0;                                              \
          bf16x8 af = *(const bf16x8*)&cA[arow + cq];                           \
          _Pragma("unroll")                                                     \
          for (int ni=0; ni<4; ++ni){                                           \
            bf16x8 bfv = *(const bf16x8*)&cB[ni*1024 + l16*64 + cq];            \
            acc[ni] = __builtin_amdgcn_mfma_f32_16x16x32_bf16(af, bfv, acc[ni], 0,0,0); \
          }                                                                     \
        }                                                                       \
        __builtin_amdgcn_sched_barrier(0);                                      \
        __builtin_amdgcn_s_barrier();                                           \
      }                                                                         \
    }

// ======== GEMM core 64x64, 3-buffer, 2-step lead, 1 barrier/step (round-7, == round-6 perf) ========
// sh must be: __shared__ __align__(16) unsigned short sh[24576];
#define GEMM_GL64_3B(A_, Bt_, M0_, n0_, M_)                                     \
    int tid = threadIdx.x;                                                      \
    int m0 = (M0_);                                                             \
    int wv = tid>>6, lane = tid&63;                                             \
    int quad = lane>>4, l16 = lane&15;                                          \
    floatx4 acc[4];                                                             \
    _Pragma("unroll")                                                           \
    for (int ni=0;ni<4;++ni) acc[ni] = (floatx4){0.f,0.f,0.f,0.f};              \
    {                                                                           \
      int rl0 = wv*16 + (lane>>3);                                              \
      int rl1 = rl0 + 8;                                                        \
      int gc  = (lane&7) ^ (lane>>3);                                           \
      int ra0 = m0 + rl0; if (ra0 > (M_)-1) ra0 = (M_)-1;                       \
      int ra1 = m0 + rl1; if (ra1 > (M_)-1) ra1 = (M_)-1;                       \
      const char* gA0 = (const char*)(A_)  + (size_t)ra0*1536 + gc*16;          \
      const char* gA1 = (const char*)(A_)  + (size_t)ra1*1536 + gc*16;          \
      const char* gB0 = (const char*)(Bt_) + (size_t)((n0_)+rl0)*1536 + gc*16;  \
      const char* gB1 = (const char*)(Bt_) + (size_t)((n0_)+rl1)*1536 + gc*16;  \
      char* shB = (char*)sh;                                                    \
      int ld0 = (2*wv)*1024, ld1 = (2*wv+1)*1024;                               \
      int arow = (16*wv + l16)*64;                                              \
      int sw8  = l16 & 7;                                                       \
      int cq0 = (quad ^ sw8)*8;                                                 \
      int cq1 = ((4|quad) ^ sw8)*8;                                             \
      gload16(gA0, shB + ld0);                                                  \
      gload16(gA1, shB + ld1);                                                  \
      gload16(gB0, shB + 8192 + ld0);                                           \
      gload16(gB1, shB + 8192 + ld1);                                           \
      gload16(gA0 + 128, shB + 16384 + ld0);                                    \
      gload16(gA1 + 128, shB + 16384 + ld1);                                    \
      gload16(gB0 + 128, shB + 16384 + 8192 + ld0);                             \
      gload16(gB1 + 128, shB + 16384 + 8192 + ld1);                             \
      for (int s=0; s<12; ++s){                                                 \
        if (s < 11) asm volatile("s_waitcnt vmcnt(4)" ::: "memory");            \
        else        asm volatile("s_waitcnt vmcnt(0)" ::: "memory");            \
        __builtin_amdgcn_s_barrier();                                           \
        __builtin_amdgcn_sched_barrier(0);                                      \
        if (s < 10){                                                            \
          char* nb = shB + ((s+2)%3)*16384;                                     \
          int off = (s+2)*128;                                                  \
          gload16(gA0 + off, nb + ld0);                                         \
          gload16(gA1 + off, nb + ld1);                                         \
          gload16(gB0 + off, nb + 8192 + ld0);                                  \
          gload16(gB1 + off, nb + 8192 + ld1);                                  \
        }                                                                       \
        __builtin_amdgcn_sched_barrier(0);                                      \
        const unsigned short* cA = sh + (s%3)*8192;                             \
        const unsigned short* cB = cA + 4096;                                   \
        _Pragma("unroll")                                                       \
        for (int kh=0; kh<2; ++kh){                                             \
          int cq = kh ? cq1 : cq0;                                              \
          bf16x8 af = *(const bf16x8*)&cA[arow + cq];                           \
          _Pragma("unroll")                                                     \
          for (int ni=0; ni<4; ++ni){                                           \
            bf16x8 bfv = *(const bf16x8*)&cB[ni*1024 + l16*64 + cq];            \
            acc[ni] = __builtin_amdgcn_mfma_f32_16x16x32_bf16(af, bfv, acc[ni], 0,0,0); \
          }                                                                     \
        }                                                                       \
        __builtin_amdgcn_sched_barrier(0);                                      \
      }                                                                         \
    }

// ---------------- standalone GEMM (N=768), 64x64 tiles, 3-buffer pipe ----------------
// MODE 1: bf16(gelu). MODE 2: resid += (plain), optionally fused LN of the completed
// resid rows via last-block-arrival counter (lnout != nullptr):
//   every block: threadfence -> 1 atomicAdd on cnt[rowblock]; 12th arrival re-reads
//   the finished fp32 rows (all col-blocks done), writes LN -> lnout, resets counter.
//   Device-scope atomics + __threadfence handle cross-XCD visibility (G12/G16).
template<int MODE>
__global__ __launch_bounds__(256)
void gemm_kernel(const unsigned short* __restrict__ A, const unsigned short* __restrict__ Bt,
                 const float* __restrict__ bias, unsigned short* __restrict__ outb,
                 float* __restrict__ resid, int M,
                 const float* __restrict__ lng, const float* __restrict__ lnb,
                 unsigned short* __restrict__ lnout, int* __restrict__ cnt){
    __shared__ __align__(16) unsigned short sh[24576];
    int n0 = blockIdx.y*64;
    GEMM_GL64_3B(A, Bt, blockIdx.x*64, n0, M)
    float bfv_[4];
    #pragma unroll
    for (int ni=0;ni<4;++ni) bfv_[ni] = bias ? bias[n0 + 16*ni + l16] : 0.0f;
    #pragma unroll
    for (int rr=0;rr<4;++rr){
        int row = m0 + 16*wv + 4*quad + rr;
        if (row >= M) continue;
        #pragma unroll
        for (int ni=0;ni<4;++ni){
            int col = n0 + 16*ni + l16;
            float v = acc[ni][rr] + bfv_[ni];
            if (MODE == 1)      outb[(size_t)row*768 + col] = f2b(0.5f*v*(1.0f + erff(v*0.70710678118654752f)));
            else                resid[(size_t)row*768 + col] += v;
        }
    }
    if (MODE == 2 && lnout){
        __threadfence();                       // flush this thread's resid stores device-wide
        __syncthreads();
        __shared__ int oldc;
        if (tid == 0) oldc = atomicAdd(cnt + blockIdx.x, 1);
        __syncthreads();
        if (oldc == (int)gridDim.y - 1){
            __threadfence();                   // acquire: see all col-blocks' resid writes
            for (int it = 0; it < 16; ++it){
                int row = m0 + it*4 + wv;      // wave-per-row, 64 rows
                if (row < M){
                    const float* xr = resid + (size_t)row*768;
                    float v[12]; float s = 0.f, ss = 0.f;
                    #pragma unroll
                    for (int j=0;j<12;++j){
                        float t = xr[lane + 64*j];
                        v[j] = t; s += t; ss += t*t;
                    }
                    #pragma unroll
                    for (int o=1;o<64;o<<=1){ s += __shfl_xor(s,o); ss += __shfl_xor(ss,o); }
                    float mean = s*(1.0f/768.0f);
                    float var  = ss*(1.0f/768.0f) - mean*mean;
                    float inv  = 1.0f/sqrtf(var + 1e-5f);
                    unsigned short* orow = lnout + (size_t)row*768;
                    #pragma unroll
                    for (int j=0;j<12;++j){
                        int i = lane + 64*j;
                        orow[i] = f2b((v[j]-mean)*inv*lng[i] + lnb[i]);
                    }
                }
            }
            if (tid == 0) atomicExch(cnt + blockIdx.x, 0);   // reset for next fused dispatch
        }
    }
}

// ---------------- fused QKV (+ layer-0: both layers' pos-projection) GEMM ----------------
// Flat grid: blocks [0,1152) = qkv (m = bid&31, ny = bid>>5); blocks [1152,1248) = pos.
// Layer-1 launch uses 1152 blocks (no pos part).
__global__ __launch_bounds__(256)
void gemm_qkv_kernel(const unsigned short* __restrict__ A, const unsigned short* __restrict__ Bt,
                     const float* __restrict__ bq, const float* __restrict__ bk, const float* __restrict__ bv,
                     unsigned short* __restrict__ qout, unsigned short* __restrict__ kout,
                     unsigned short* __restrict__ vout,
                     const unsigned short* __restrict__ peA, const unsigned short* __restrict__ posBt,
                     unsigned short* __restrict__ ppout){
    __shared__ __align__(16) unsigned short sh[16384];
    int bid = blockIdx.x;
    if (bid < 1152){
        int ny = bid >> 5;
        int n0 = ny * 64;
        GEMM_GL64(A, Bt, (bid & 31)*64, n0, 2000)
        int sec = ny / 12;                    // 0=q 1=k 2=v
        int col0 = n0 - sec*768;
        int h = col0 >> 6;
        const float* bias = (sec==0) ? bq : (sec==1) ? bk : bv;
        float bfv_[4];
        #pragma unroll
        for (int ni=0;ni<4;++ni) bfv_[ni] = bias[col0 + 16*ni + l16];
        if (sec != 2){
            unsigned short* outp = (sec==0) ? qout : kout;
            #pragma unroll
            for (int rr=0;rr<4;++rr){
                int row = m0 + 16*wv + 4*quad + rr;
                if (row >= 2000) continue;
                int b = row / TT, tl = row - b*TT;
                #pragma unroll
                for (int ni=0;ni<4;++ni){
                    int d = 16*ni + l16;
                    outp[(((size_t)(b*HH + h))*TT + tl)*DK + d] = f2b(acc[ni][rr] + bfv_[ni]);
                }
            }
        } else {
            // V: acc tile -> LDS scratch (stride 66, bytes 0..8447 = buf0; last K-step read buf1 -> disjoint)
            #pragma unroll
            for (int rr=0;rr<4;++rr){
                int rt = 16*wv + 4*quad + rr;
                #pragma unroll
                for (int ni=0;ni<4;++ni)
                    sh[rt*66 + 16*ni + l16] = f2b(acc[ni][rr] + bfv_[ni]);
            }
            __syncthreads();
            #pragma unroll
            for (int it=0; it<16; ++it){
                int idx = it*256 + tid;            // 64*64 = 4096 = 16*256
                int d = idx >> 6, rt = idx & 63;
                int row = m0 + rt;
                if (row < 2000){
                    int b = row / TT, tl = row - b*TT;
                    vout[(((size_t)(b*HH + h))*DK + d)*VTP + tl + 128] = sh[rt*66 + d];
                }
            }
        }
    } else {
        int pid = bid - 1152;                 // 0..95
        int pz = pid / 48, rem = pid % 48;    // pz = layer
        int pn0 = (rem >> 2) * 64;
        const unsigned short* Bt_ = posBt + (size_t)pz*7*WELEM;
        unsigned short* outb_ = ppout + (size_t)pz*PPL;
        GEMM_GL64(peA, Bt_, (rem & 3)*64, pn0, PEROWS)
        #pragma unroll
        for (int rr=0;rr<4;++rr){
            int row = m0 + 16*wv + 4*quad + rr;
            if (row >= PEROWS) continue;
            #pragma unroll
            for (int ni=0;ni<4;++ni){
                int col = pn0 + 16*ni + l16;
                int h = col >> 6, d = col & 63;
                outb_[((size_t)h*PEROWS + row)*DK + d] = f2b(acc[ni][rr]);
            }
        }
    }
}

// ---------------- MFMA banded rel-pos attention: 4 waves cooperate on one 16-row t-tile ----------------
// No-max softmax (scores bounded; masked lanes -1e30 -> exp = 0). Also zeroes the
// LN-fusion counters (cnt, 32 ints) in one block — they live in dead pebuf space.
__global__ __launch_bounds__(256)
void attn_kernel(const unsigned short* __restrict__ q, const unsigned short* __restrict__ k,
                 const unsigned short* __restrict__ vT, const unsigned short* __restrict__ pp,
                 const float* __restrict__ pbu, const float* __restrict__ pbv,
                 unsigned short* __restrict__ out, int* __restrict__ cnt){
    int b = blockIdx.y, h = HORD[blockIdx.z];
    int t0 = blockIdx.x * 16;
    int w2 = HALFW[h];
    int tid = threadIdx.x;
    int wv = tid >> 6, lane = tid & 63;
    int l16 = lane & 15, quad = lane >> 4;

    if (blockIdx.x == 0 && blockIdx.y == 0 && blockIdx.z == 0 && tid < 32)
        atomicExch(cnt + tid, 0);

    const unsigned short* qB = q  + ((size_t)(b*HH + h))*TT*DK;
    const unsigned short* kB = k  + ((size_t)(b*HH + h))*TT*DK;
    const unsigned short* vB = vT + ((size_t)(b*HH + h))*DK*VTP;
    const unsigned short* pB = pp + (size_t)h*PEROWS*DK;

    __shared__ __align__(16) float bd[16*260];
    __shared__ __align__(16) unsigned short pl[16*328];
    __shared__ float sms[4][16];

    int tq = t0 + l16; if (tq > TT-1) tq = TT-1;
    union { int4 i; unsigned short u[8]; } r0, r1;
    r0.i = *(const int4*)(qB + (size_t)tq*DK + quad*8);
    r1.i = *(const int4*)(qB + (size_t)tq*DK + 32 + quad*8);
    const float* pu = pbu + h*DK + quad*8;
    const float* pv = pbv + h*DK + quad*8;
    union { unsigned short u[8]; bf16x8 v; } qu0, qu1, qv0, qv1;
    #pragma unroll
    for (int i=0;i<8;++i){
        float a0 = b2f(r0.u[i]), a1 = b2f(r1.u[i]);
        qu0.u[i] = f2b(a0 + pu[i]);
        qu1.u[i] = f2b(a1 + pu[32+i]);
        qv0.u[i] = f2b(a0 + pv[i]);
        qv1.u[i] = f2b(a1 + pv[32+i]);
    }

    int Nn = 2*w2 + 1;
    int ntiles = (Nn + 15) >> 4;
    for (int ti = wv; ti < ntiles; ti += 4){
        int n = 127 - w2 + ti*16 + l16; if (n > PEROWS-1) n = PEROWS-1;
        const unsigned short* pr = pB + (size_t)n*DK + quad*8;
        bf16x8 pb0 = *(const bf16x8*)pr;
        bf16x8 pb1 = *(const bf16x8*)(pr + 32);
        floatx4 a = {0.f,0.f,0.f,0.f};
        a = __builtin_amdgcn_mfma_f32_16x16x32_bf16(qv0.v, pb0, a, 0,0,0);
        a = __builtin_amdgcn_mfma_f32_16x16x32_bf16(qv1.v, pb1, a, 0,0,0);
        #pragma unroll
        for (int r=0;r<4;++r) bd[(quad*4+r)*260 + ti*16 + l16] = a[r];
    }
    for (int i = tid; i < 16*328/4; i += 256)
        ((unsigned long long*)pl)[i] = 0ULL;
    __syncthreads();                                     // barrier 1

    int Ns = 2*w2 + 16;
    int stiles = (Ns + 15) >> 4;
    int s_lo = t0 - w2;
    float scv[5][4];
    #pragma unroll
    for (int ii = 0; ii < 5; ++ii){
        int ti = wv + ii*4;
        if (ti < stiles){
            int s = s_lo + ti*16 + l16;
            int sc = s < 0 ? 0 : (s > TT-1 ? TT-1 : s);
            const unsigned short* kr = kB + (size_t)sc*DK + quad*8;
            bf16x8 kb0 = *(const bf16x8*)kr;
            bf16x8 kb1 = *(const bf16x8*)(kr + 32);
            floatx4 a = {0.f,0.f,0.f,0.f};
            a = __builtin_amdgcn_mfma_f32_16x16x32_bf16(qu0.v, kb0, a, 0,0,0);
            a = __builtin_amdgcn_mfma_f32_16x16x32_bf16(qu1.v, kb1, a, 0,0,0);
            #pragma unroll
            for (int r=0;r<4;++r){
                int row = quad*4 + r;
                int nrel = ti*16 + l16 - row;
                bool ok = (nrel >= 0) && (nrel <= 2*w2) && (s >= 0) && (s <= TT-1);
                int idx = row*260 + nrel;
                idx = idx < 0 ? 0 : (idx > 16*260-1 ? 16*260-1 : idx);
                float bdv = bd[idx];
                scv[ii][r] = ok ? (a[r] + bdv) * 0.125f : -1e30f;
            }
        } else {
            #pragma unroll
            for (int r=0;r<4;++r) scv[ii][r] = -1e30f;
        }
    }

    float sm[4] = {0.f,0.f,0.f,0.f};
    #pragma unroll
    for (int ii = 0; ii < 5; ++ii){
        int ti = wv + ii*4;
        if (ti < stiles){
            int pad_base = (t0 - w2) - ((t0 - w2) & ~31);
            #pragma unroll
            for (int r=0;r<4;++r){
                float e = __expf(scv[ii][r]);        // no-max softmax (bounded scores)
                sm[r] += e;
                pl[(quad*4+r)*328 + pad_base + ti*16 + l16] = f2b(e);
            }
        }
    }
    #pragma unroll
    for (int off=1; off<16; off<<=1){
        #pragma unroll
        for (int r=0;r<4;++r) sm[r] += __shfl_xor(sm[r], off);
    }
    if (l16 == 0){
        #pragma unroll
        for (int r=0;r<4;++r) sms[wv][quad*4+r] = sm[r];
    }
    __syncthreads();                                     // barrier 2

    int s_lo2 = t0 - w2;
    int s0a = s_lo2 & ~31;
    int pad_lo = s_lo2 - s0a;
    int ktiles = (pad_lo + Ns + 31) >> 5;

    floatx4 oacc = {0.f,0.f,0.f,0.f};
    for (int kt = 0; kt < ktiles; ++kt){
        bf16x8 pa = *(const bf16x8*)&pl[l16*328 + kt*32 + quad*8];
        int sidx = s0a + kt*32 + quad*8 + 128;
        bf16x8 vb = *(const bf16x8*)(vB + (size_t)(wv*16 + l16)*VTP + sidx);
        oacc = __builtin_amdgcn_mfma_f32_16x16x32_bf16(pa, vb, oacc, 0,0,0);
    }
    #pragma unroll
    for (int r=0;r<4;++r){
        int row = quad*4 + r;
        float sum = sms[0][row] + sms[1][row] + sms[2][row] + sms[3][row];
        float rinv = sum > 0.f ? 1.0f/sum : 0.0f;
        int t = t0 + row;
        if (t <= TT-1)
            out[(((size_t)(b*TT + t))*HH + h)*DK + wv*16 + l16] = f2b(oacc[r] * rinv);
    }
}

// ---------------- launcher (11 dispatches, was 16) ----------------
extern "C" void kernel_launch(void* const* d_in, const int* in_sizes, int n_in,
                              void* d_out, int out_size, void* d_ws, size_t ws_size,
                              hipStream_t stream){
    const float* x    = (const float*)d_in[0];
    const float* ln1g = (const float*)d_in[2];
    const float* ln1b = (const float*)d_in[3];
    const float* wq   = (const float*)d_in[4];
    const float* bq   = (const float*)d_in[5];
    const float* wk   = (const float*)d_in[6];
    const float* bk   = (const float*)d_in[7];
    const float* wvv  = (const float*)d_in[8];
    const float* bv   = (const float*)d_in[9];
    const float* wo   = (const float*)d_in[10];
    const float* bo   = (const float*)d_in[11];
    const float* wpos = (const float*)d_in[12];
    const float* pbu  = (const float*)d_in[13];
    const float* pbv  = (const float*)d_in[14];
    const float* ln2g = (const float*)d_in[15];
    const float* ln2b = (const float*)d_in[16];
    const float* w1   = (const float*)d_in[17];
    const float* b1   = (const float*)d_in[18];
    const float* w2   = (const float*)d_in[19];
    const float* b2   = (const float*)d_in[20];

    const int NTOK = BB*TT;            // 2000

    float* x_cur = (float*)d_out;      // residual in d_out (fp32)

    // ws layout — total 30,936,576 B
    char* ws = (char*)d_ws;
    unsigned short* qbuf  = (unsigned short*)(ws);              // (b,h,t,d) q / mlp hidden
    unsigned short* kbuf  = (unsigned short*)(ws + 3072000);    // (b,h,t,d)
    unsigned short* vTbuf = (unsigned short*)(ws + 6144000);    // (b,h,d,t+128) 4,030,464 B
    unsigned short* hbuf  = (unsigned short*)(ws + 10174464);   // ln out / attn out
    unsigned short* ppbuf = (unsigned short*)(ws + 13246464);   // (l,h,n,d) 783,360 B
    unsigned short* pebuf = (unsigned short*)(ws + 14029824);   // 391,680 B (dead after pos)
    unsigned short* wtbuf = (unsigned short*)(ws + 14421504);   // 14 * 1,179,648 B
    int* cnt = (int*)pebuf;            // 32 ints; pebuf is dead after the pos dispatch
    #define WT(t_,l_) (wtbuf + (size_t)((l_)*7 + (t_))*WELEM)

    dim3 blk(256);
    // merged preamble: wconv (z<14) + scale+layer0-ln1 (z=14) + pe (z=15)
    prep_kernel<<<dim3(12,12,16), blk, 0, stream>>>(wq, wk, wvv, wo, wpos, w1, w2,
                                                    wtbuf, x, x_cur, pebuf,
                                                    ln1g, ln1b, hbuf);

    dim3 gBig(32, 12);                 // 64x64 tiles (384 blocks)
    dim3 gAttn(63, BB, HH);

    for (int l = 0; l < LL; ++l){
        long dl = (long)l*DD;
        long pl_ = (long)l*HH*DK;

        // qkv (layer-0 launch also carries both layers' pos projections: +96 blocks)
        int nqkv = (l == 0) ? 1248 : 1152;
        gemm_qkv_kernel<<<dim3(nqkv), blk, 0, stream>>>(hbuf, WT(0,l), bq + dl, bk + dl, bv + dl,
                                                        qbuf, kbuf, vTbuf,
                                                        pebuf, WT(4,0), ppbuf);

        attn_kernel<<<gAttn, blk, 0, stream>>>(qbuf, kbuf, vTbuf, ppbuf + (size_t)l*PPL,
                                               pbu + pl_, pbv + pl_, hbuf, cnt);

        // o-proj resid += , fused ln2 (winner blocks write hbuf)
        gemm_kernel<2><<<gBig, blk, 0, stream>>>(hbuf, WT(3,l), bo + dl, nullptr, x_cur, NTOK,
                                                 ln2g + dl, ln2b + dl, hbuf, cnt);

        // mlp1: gelu -> qbuf
        gemm_kernel<1><<<gBig, blk, 0, stream>>>(hbuf, WT(5,l), b1 + dl, qbuf, nullptr, NTOK,
                                                 nullptr, nullptr, nullptr, nullptr);

        // mlp2: resid += ; layer 0 fuses next layer's ln1, layer 1 is final (no LN)
        if (l == 0)
            gemm_kernel<2><<<gBig, blk, 0, stream>>>(qbuf, WT(6,l), b2 + dl, nullptr, x_cur, NTOK,
                                                     ln1g + DD, ln1b + DD, hbuf, cnt);
        else
            gemm_kernel<2><<<gBig, blk, 0, stream>>>(qbuf, WT(6,l), b2 + dl, nullptr, x_cur, NTOK,
                                                     nullptr, nullptr, nullptr, nullptr);
    }
}

// Round 9
// 275.996 us; speedup vs baseline: 1.5235x; 1.5235x over previous
//
#include <hip/hip_runtime.h>

// ---------------- constants ----------------
#define TT 1000
#define BB 2
#define DD 768
#define HH 12
#define DK 64
#define LL 2
#define WELEM 589824          // 768*768
#define PEROWS 255            // rel positions -127..127
#define VTP 1312              // t-stride in vT layout (with 128 margin both sides)
#define PPL 195840            // per-layer pp elems: HH*PEROWS*DK

typedef __bf16 bf16x8 __attribute__((ext_vector_type(8)));
typedef float floatx4 __attribute__((ext_vector_type(4)));

__device__ __constant__ int HALFW[12] = {3,7,15,31,63,127,3,7,15,31,63,127};
__device__ __constant__ int HORD[12]  = {5,11,4,10,3,9,2,8,1,7,0,6};   // heavy bands first

// LESSON (round 8): per-block __threadfence() on gfx950 = per-XCD L2 writeback/invalidate
// storm (L2s not cross-coherent). 3 fused dispatches went 6us -> 65us each, MfmaUtil 1.3%.
// Never use device-scope fences per-block for producer/consumer LN fusion here.

// ---------------- helpers ----------------
__device__ __forceinline__ float b2f(unsigned short u){
    union { unsigned int i; float f; } x; x.i = ((unsigned int)u) << 16; return x.f;
}
__device__ __forceinline__ unsigned short f2b(float f){
    union { float f; unsigned int i; } x; x.f = f;
    unsigned int i = x.i;
    i += 0x7fffu + ((i >> 16) & 1u);   // RNE
    return (unsigned short)(i >> 16);
}
// async global->LDS, 16B per lane; lds dest is wave-uniform base + lane*16
__device__ __forceinline__ void gload16(const void* g, void* l){
    __builtin_amdgcn_global_load_lds(
        (const __attribute__((address_space(1))) void*)g,
        (__attribute__((address_space(3))) void*)l, 16, 0, 0);
}

// ---------------- merged preamble: z<14 wconv slice; z=14 x-scale + layer0-ln1; z=15 pe ----------------
__global__ __launch_bounds__(256)
void prep_kernel(const float* s0, const float* s1, const float* s2, const float* s3,
                 const float* s4, const float* s5, const float* s6,
                 unsigned short* __restrict__ dst,
                 const float* __restrict__ x, float* __restrict__ xc,
                 unsigned short* __restrict__ pe,
                 const float* __restrict__ lg0, const float* __restrict__ lb0,
                 unsigned short* __restrict__ ln0out){
    int z = blockIdx.z;
    int tid = threadIdx.x;
    if (z < 14){
        const float* srcs[7] = {s0,s1,s2,s3,s4,s5,s6};
        const float* src = srcs[z % 7] + (size_t)(z / 7)*WELEM;
        unsigned short* d = dst + (size_t)z*WELEM;
        int k0 = blockIdx.x*64, n0 = blockIdx.y*64;
        __shared__ __align__(16) unsigned short tile[64][72];
        int r = tid >> 2, c = tid & 3;
        const float4* sp = (const float4*)(src + (size_t)(k0+r)*DD + n0 + c*16);
        float4 f0 = sp[0], f1 = sp[1], f2 = sp[2], f3 = sp[3];
        unsigned short u[16];
        u[0]=f2b(f0.x); u[1]=f2b(f0.y); u[2]=f2b(f0.z); u[3]=f2b(f0.w);
        u[4]=f2b(f1.x); u[5]=f2b(f1.y); u[6]=f2b(f1.z); u[7]=f2b(f1.w);
        u[8]=f2b(f2.x); u[9]=f2b(f2.y); u[10]=f2b(f2.z); u[11]=f2b(f2.w);
        u[12]=f2b(f3.x); u[13]=f2b(f3.y); u[14]=f2b(f3.z); u[15]=f2b(f3.w);
        *(int4*)&tile[r][c*16]   = *(int4*)&u[0];
        *(int4*)&tile[r][c*16+8] = *(int4*)&u[8];
        __syncthreads();
        unsigned short tmp[16];
        #pragma unroll
        for (int i=0;i<16;++i) tmp[i] = tile[c*16+i][r];
        int4* dp = (int4*)(d + (size_t)(n0+r)*DD + k0 + c*16);
        dp[0] = *(int4*)&tmp[0];
        dp[1] = *(int4*)&tmp[8];
    } else if (z == 14){
        // x-scale + layer-0 ln1 fused: wave-per-row, 14 rows per block instance (fence-free)
        int bid = blockIdx.y*12 + blockIdx.x;         // 0..143
        int wv = tid>>6, lane = tid&63;
        const float SCL = 27.712812921102035f;
        #pragma unroll
        for (int it = 0; it < 4; ++it){
            int rr = it*4 + wv;                       // 0..15
            if (rr < 14){
                int row = bid*14 + rr;
                if (row < 2000){
                    const float4* xr = (const float4*)x + (size_t)row*192;
                    float4* xcr = (float4*)xc + (size_t)row*192;
                    float4 vv[3];
                    float s = 0.f, ss = 0.f;
                    #pragma unroll
                    for (int j=0;j<3;++j){
                        float4 vq = xr[lane + 64*j];
                        vq.x *= SCL; vq.y *= SCL; vq.z *= SCL; vq.w *= SCL;
                        vv[j] = vq;
                        s  += vq.x+vq.y+vq.z+vq.w;
                        ss += vq.x*vq.x+vq.y*vq.y+vq.z*vq.z+vq.w*vq.w;
                        xcr[lane + 64*j] = vq;
                    }
                    #pragma unroll
                    for (int o=1;o<64;o<<=1){ s += __shfl_xor(s,o); ss += __shfl_xor(ss,o); }
                    float mean = s*(1.0f/768.0f);
                    float var  = ss*(1.0f/768.0f) - mean*mean;
                    float inv  = 1.0f/sqrtf(var + 1e-5f);
                    unsigned short* orow = ln0out + (size_t)row*768;
                    #pragma unroll
                    for (int j=0;j<3;++j){
                        int i0 = (lane + 64*j)*4;
                        unsigned short o4[4];
                        o4[0] = f2b((vv[j].x-mean)*inv*lg0[i0]   + lb0[i0]);
                        o4[1] = f2b((vv[j].y-mean)*inv*lg0[i0+1] + lb0[i0+1]);
                        o4[2] = f2b((vv[j].z-mean)*inv*lg0[i0+2] + lb0[i0+2]);
                        o4[3] = f2b((vv[j].w-mean)*inv*lg0[i0+3] + lb0[i0+3]);
                        *(unsigned long long*)&orow[i0] = *(unsigned long long*)o4;
                    }
                }
            }
        }
    } else {
        int bid = blockIdx.y*12 + blockIdx.x;         // 0..143
        #pragma unroll
        for (int rr = 0; rr < 2; ++rr){
            int row = bid*2 + rr;
            if (row < PEROWS){
                float pos = (float)(127 - row);
                int i = tid;
                float dv = expf((float)(2*i) * (-9.210340371976184f / 768.0f));
                float ang = pos * dv;
                pe[(size_t)row*DD + 2*i]   = f2b(sinf(ang));
                pe[(size_t)row*DD + 2*i+1] = f2b(cosf(ang));
                if (tid < 128){
                    int j = 256 + tid;
                    float dv2 = expf((float)(2*j) * (-9.210340371976184f / 768.0f));
                    float an2 = pos * dv2;
                    pe[(size_t)row*DD + 2*j]   = f2b(sinf(an2));
                    pe[(size_t)row*DD + 2*j+1] = f2b(cosf(an2));
                }
            }
        }
    }
}

// ---------------- LayerNorm: fp32 in -> bf16 out ----------------
__global__ __launch_bounds__(256)
void ln_kernel(const float* __restrict__ x, const float* __restrict__ g,
               const float* __restrict__ bb, unsigned short* __restrict__ out){
    int row = blockIdx.x;
    const float* xr = x + (size_t)row*DD;
    int tid = threadIdx.x;
    float v0 = xr[tid], v1 = xr[tid+256], v2 = xr[tid+512];
    float s = v0+v1+v2, ss = v0*v0+v1*v1+v2*v2;
    #pragma unroll
    for (int o=1;o<64;o<<=1){ s += __shfl_xor(s,o); ss += __shfl_xor(ss,o); }
    __shared__ float rs[4], rss[4];
    int wv = tid>>6, lane = tid&63;
    if (lane==0){ rs[wv]=s; rss[wv]=ss; }
    __syncthreads();
    s  = rs[0]+rs[1]+rs[2]+rs[3];
    ss = rss[0]+rss[1]+rss[2]+rss[3];
    float mean = s * (1.0f/768.0f);
    float var  = ss * (1.0f/768.0f) - mean*mean;
    float inv  = 1.0f / sqrtf(var + 1e-5f);
    unsigned short* orow = out + (size_t)row*DD;
    #pragma unroll
    for (int kk=0;kk<3;++kk){
        int i = tid + 256*kk;
        float v = (kk==0?v0:(kk==1?v1:v2));
        orow[i] = f2b((v - mean)*inv*g[i] + bb[i]);
    }
}

// ======== GEMM core 64x64, 2-buffer, counted vmcnt (round-6 verified) ========
// sh must be: __shared__ __align__(16) unsigned short sh[16384];
#define GEMM_GL64(A_, Bt_, M0_, n0_, M_)                                        \
    int tid = threadIdx.x;                                                      \
    int m0 = (M0_);                                                             \
    int wv = tid>>6, lane = tid&63;                                             \
    int quad = lane>>4, l16 = lane&15;                                          \
    floatx4 acc[4];                                                             \
    _Pragma("unroll")                                                           \
    for (int ni=0;ni<4;++ni) acc[ni] = (floatx4){0.f,0.f,0.f,0.f};              \
    {                                                                           \
      int rl0 = wv*16 + (lane>>3);                                              \
      int rl1 = rl0 + 8;                                                        \
      int gc  = (lane&7) ^ (lane>>3);                                           \
      int ra0 = m0 + rl0; if (ra0 > (M_)-1) ra0 = (M_)-1;                       \
      int ra1 = m0 + rl1; if (ra1 > (M_)-1) ra1 = (M_)-1;                       \
      const char* gA0 = (const char*)(A_)  + (size_t)ra0*1536 + gc*16;          \
      const char* gA1 = (const char*)(A_)  + (size_t)ra1*1536 + gc*16;          \
      const char* gB0 = (const char*)(Bt_) + (size_t)((n0_)+rl0)*1536 + gc*16;  \
      const char* gB1 = (const char*)(Bt_) + (size_t)((n0_)+rl1)*1536 + gc*16;  \
      char* shB = (char*)sh;                                                    \
      int ld0 = (2*wv)*1024, ld1 = (2*wv+1)*1024;                               \
      int arow = (16*wv + l16)*64;                                              \
      int sw8  = l16 & 7;                                                       \
      int cq0 = (quad ^ sw8)*8;                                                 \
      int cq1 = ((4|quad) ^ sw8)*8;                                             \
      gload16(gA0, shB + ld0);                                                  \
      gload16(gA1, shB + ld1);                                                  \
      gload16(gB0, shB + 8192 + ld0);                                           \
      gload16(gB1, shB + 8192 + ld1);                                           \
      for (int s=0; s<12; ++s){                                                 \
        if (s < 11){                                                            \
          char* nb = shB + ((s+1)&1)*16384;                                     \
          int off = (s+1)*128;                                                  \
          gload16(gA0 + off, nb + ld0);                                         \
          gload16(gA1 + off, nb + ld1);                                         \
          gload16(gB0 + off, nb + 8192 + ld0);                                  \
          gload16(gB1 + off, nb + 8192 + ld1);                                  \
          asm volatile("s_waitcnt vmcnt(4)" ::: "memory");                      \
        } else {                                                                \
          asm volatile("s_waitcnt vmcnt(0)" ::: "memory");                      \
        }                                                                       \
        __builtin_amdgcn_s_barrier();                                           \
        __builtin_amdgcn_sched_barrier(0);                                      \
        const unsigned short* cA = sh + (s&1)*8192;                             \
        const unsigned short* cB = cA + 4096;                                   \
        _Pragma("unroll")                                                       \
        for (int kh=0; kh<2; ++kh){                                             \
          int cq = kh ? cq1 : cq0;                                              \
          bf16x8 af = *(const bf16x8*)&cA[arow + cq];                           \
          _Pragma("unroll")                                                     \
          for (int ni=0; ni<4; ++ni){                                           \
            bf16x8 bfv = *(const bf16x8*)&cB[ni*1024 + l16*64 + cq];            \
            acc[ni] = __builtin_amdgcn_mfma_f32_16x16x32_bf16(af, bfv, acc[ni], 0,0,0); \
          }                                                                     \
        }                                                                       \
        __builtin_amdgcn_sched_barrier(0);                                      \
        __builtin_amdgcn_s_barrier();                                           \
      }                                                                         \
    }

// ======== GEMM core 64x64, 3-buffer, 2-step lead, 1 barrier/step (round-7 verified) ========
// sh must be: __shared__ __align__(16) unsigned short sh[24576];
#define GEMM_GL64_3B(A_, Bt_, M0_, n0_, M_)                                     \
    int tid = threadIdx.x;                                                      \
    int m0 = (M0_);                                                             \
    int wv = tid>>6, lane = tid&63;                                             \
    int quad = lane>>4, l16 = lane&15;                                          \
    floatx4 acc[4];                                                             \
    _Pragma("unroll")                                                           \
    for (int ni=0;ni<4;++ni) acc[ni] = (floatx4){0.f,0.f,0.f,0.f};              \
    {                                                                           \
      int rl0 = wv*16 + (lane>>3);                                              \
      int rl1 = rl0 + 8;                                                        \
      int gc  = (lane&7) ^ (lane>>3);                                           \
      int ra0 = m0 + rl0; if (ra0 > (M_)-1) ra0 = (M_)-1;                       \
      int ra1 = m0 + rl1; if (ra1 > (M_)-1) ra1 = (M_)-1;                       \
      const char* gA0 = (const char*)(A_)  + (size_t)ra0*1536 + gc*16;          \
      const char* gA1 = (const char*)(A_)  + (size_t)ra1*1536 + gc*16;          \
      const char* gB0 = (const char*)(Bt_) + (size_t)((n0_)+rl0)*1536 + gc*16;  \
      const char* gB1 = (const char*)(Bt_) + (size_t)((n0_)+rl1)*1536 + gc*16;  \
      char* shB = (char*)sh;                                                    \
      int ld0 = (2*wv)*1024, ld1 = (2*wv+1)*1024;                               \
      int arow = (16*wv + l16)*64;                                              \
      int sw8  = l16 & 7;                                                       \
      int cq0 = (quad ^ sw8)*8;                                                 \
      int cq1 = ((4|quad) ^ sw8)*8;                                             \
      gload16(gA0, shB + ld0);                                                  \
      gload16(gA1, shB + ld1);                                                  \
      gload16(gB0, shB + 8192 + ld0);                                           \
      gload16(gB1, shB + 8192 + ld1);                                           \
      gload16(gA0 + 128, shB + 16384 + ld0);                                    \
      gload16(gA1 + 128, shB + 16384 + ld1);                                    \
      gload16(gB0 + 128, shB + 16384 + 8192 + ld0);                             \
      gload16(gB1 + 128, shB + 16384 + 8192 + ld1);                             \
      for (int s=0; s<12; ++s){                                                 \
        if (s < 11) asm volatile("s_waitcnt vmcnt(4)" ::: "memory");            \
        else        asm volatile("s_waitcnt vmcnt(0)" ::: "memory");            \
        __builtin_amdgcn_s_barrier();                                           \
        __builtin_amdgcn_sched_barrier(0);                                      \
        if (s < 10){                                                            \
          char* nb = shB + ((s+2)%3)*16384;                                     \
          int off = (s+2)*128;                                                  \
          gload16(gA0 + off, nb + ld0);                                         \
          gload16(gA1 + off, nb + ld1);                                         \
          gload16(gB0 + off, nb + 8192 + ld0);                                  \
          gload16(gB1 + off, nb + 8192 + ld1);                                  \
        }                                                                       \
        __builtin_amdgcn_sched_barrier(0);                                      \
        const unsigned short* cA = sh + (s%3)*8192;                             \
        const unsigned short* cB = cA + 4096;                                   \
        _Pragma("unroll")                                                       \
        for (int kh=0; kh<2; ++kh){                                             \
          int cq = kh ? cq1 : cq0;                                              \
          bf16x8 af = *(const bf16x8*)&cA[arow + cq];                           \
          _Pragma("unroll")                                                     \
          for (int ni=0; ni<4; ++ni){                                           \
            bf16x8 bfv = *(const bf16x8*)&cB[ni*1024 + l16*64 + cq];            \
            acc[ni] = __builtin_amdgcn_mfma_f32_16x16x32_bf16(af, bfv, acc[ni], 0,0,0); \
          }                                                                     \
        }                                                                       \
        __builtin_amdgcn_sched_barrier(0);                                      \
      }                                                                         \
    }

// ---------------- standalone GEMM (N=768), 64x64 tiles (384 blocks), 3-buffer pipe ----------------
// MODE 1: bf16(gelu). MODE 2: resid += (plain). (round-7 verified; NO fence-based LN fusion)
template<int MODE>
__global__ __launch_bounds__(256)
void gemm_kernel(const unsigned short* __restrict__ A, const unsigned short* __restrict__ Bt,
                 const float* __restrict__ bias, unsigned short* __restrict__ outb,
                 float* __restrict__ resid, int M){
    __shared__ __align__(16) unsigned short sh[24576];
    int n0 = blockIdx.y*64;
    GEMM_GL64_3B(A, Bt, blockIdx.x*64, n0, M)
    float bfv_[4];
    #pragma unroll
    for (int ni=0;ni<4;++ni) bfv_[ni] = bias ? bias[n0 + 16*ni + l16] : 0.0f;
    #pragma unroll
    for (int rr=0;rr<4;++rr){
        int row = m0 + 16*wv + 4*quad + rr;
        if (row >= M) continue;
        #pragma unroll
        for (int ni=0;ni<4;++ni){
            int col = n0 + 16*ni + l16;
            float v = acc[ni][rr] + bfv_[ni];
            if (MODE == 1)      outb[(size_t)row*768 + col] = f2b(0.5f*v*(1.0f + erff(v*0.70710678118654752f)));
            else                resid[(size_t)row*768 + col] += v;
        }
    }
}

// ---------------- fused QKV (+ layer-0: both layers' pos-projection) GEMM ----------------
// Flat grid: blocks [0,1152) = qkv (m = bid&31, ny = bid>>5); blocks [1152,1248) = pos.
// Layer-1 launch uses 1152 blocks (no pos part). Fence-free fusion (independent outputs).
__global__ __launch_bounds__(256)
void gemm_qkv_kernel(const unsigned short* __restrict__ A, const unsigned short* __restrict__ Bt,
                     const float* __restrict__ bq, const float* __restrict__ bk, const float* __restrict__ bv,
                     unsigned short* __restrict__ qout, unsigned short* __restrict__ kout,
                     unsigned short* __restrict__ vout,
                     const unsigned short* __restrict__ peA, const unsigned short* __restrict__ posBt,
                     unsigned short* __restrict__ ppout){
    __shared__ __align__(16) unsigned short sh[16384];
    int bid = blockIdx.x;
    if (bid < 1152){
        int ny = bid >> 5;
        int n0 = ny * 64;
        GEMM_GL64(A, Bt, (bid & 31)*64, n0, 2000)
        int sec = ny / 12;                    // 0=q 1=k 2=v
        int col0 = n0 - sec*768;
        int h = col0 >> 6;
        const float* bias = (sec==0) ? bq : (sec==1) ? bk : bv;
        float bfv_[4];
        #pragma unroll
        for (int ni=0;ni<4;++ni) bfv_[ni] = bias[col0 + 16*ni + l16];
        if (sec != 2){
            unsigned short* outp = (sec==0) ? qout : kout;
            #pragma unroll
            for (int rr=0;rr<4;++rr){
                int row = m0 + 16*wv + 4*quad + rr;
                if (row >= 2000) continue;
                int b = row / TT, tl = row - b*TT;
                #pragma unroll
                for (int ni=0;ni<4;++ni){
                    int d = 16*ni + l16;
                    outp[(((size_t)(b*HH + h))*TT + tl)*DK + d] = f2b(acc[ni][rr] + bfv_[ni]);
                }
            }
        } else {
            // V: acc tile -> LDS scratch (stride 66, bytes 0..8447 = buf0; last K-step read buf1 -> disjoint)
            #pragma unroll
            for (int rr=0;rr<4;++rr){
                int rt = 16*wv + 4*quad + rr;
                #pragma unroll
                for (int ni=0;ni<4;++ni)
                    sh[rt*66 + 16*ni + l16] = f2b(acc[ni][rr] + bfv_[ni]);
            }
            __syncthreads();
            #pragma unroll
            for (int it=0; it<16; ++it){
                int idx = it*256 + tid;            // 64*64 = 4096 = 16*256
                int d = idx >> 6, rt = idx & 63;
                int row = m0 + rt;
                if (row < 2000){
                    int b = row / TT, tl = row - b*TT;
                    vout[(((size_t)(b*HH + h))*DK + d)*VTP + tl + 128] = sh[rt*66 + d];
                }
            }
        }
    } else {
        int pid = bid - 1152;                 // 0..95
        int pz = pid / 48, rem = pid % 48;    // pz = layer
        int pn0 = (rem >> 2) * 64;
        const unsigned short* Bt_ = posBt + (size_t)pz*7*WELEM;
        unsigned short* outb_ = ppout + (size_t)pz*PPL;
        GEMM_GL64(peA, Bt_, (rem & 3)*64, pn0, PEROWS)
        #pragma unroll
        for (int rr=0;rr<4;++rr){
            int row = m0 + 16*wv + 4*quad + rr;
            if (row >= PEROWS) continue;
            #pragma unroll
            for (int ni=0;ni<4;++ni){
                int col = pn0 + 16*ni + l16;
                int h = col >> 6, d = col & 63;
                outb_[((size_t)h*PEROWS + row)*DK + d] = f2b(acc[ni][rr]);
            }
        }
    }
}

// ---------------- MFMA banded rel-pos attention: 4 waves cooperate on one 16-row t-tile ----------------
// No-max softmax: scores bounded (|s| <~ 3); masked lanes -1e30 -> exp = 0 exactly.
__global__ __launch_bounds__(256)
void attn_kernel(const unsigned short* __restrict__ q, const unsigned short* __restrict__ k,
                 const unsigned short* __restrict__ vT, const unsigned short* __restrict__ pp,
                 const float* __restrict__ pbu, const float* __restrict__ pbv,
                 unsigned short* __restrict__ out){
    int b = blockIdx.y, h = HORD[blockIdx.z];
    int t0 = blockIdx.x * 16;
    int w2 = HALFW[h];
    int tid = threadIdx.x;
    int wv = tid >> 6, lane = tid & 63;
    int l16 = lane & 15, quad = lane >> 4;

    const unsigned short* qB = q  + ((size_t)(b*HH + h))*TT*DK;
    const unsigned short* kB = k  + ((size_t)(b*HH + h))*TT*DK;
    const unsigned short* vB = vT + ((size_t)(b*HH + h))*DK*VTP;
    const unsigned short* pB = pp + (size_t)h*PEROWS*DK;

    __shared__ __align__(16) float bd[16*260];
    __shared__ __align__(16) unsigned short pl[16*328];
    __shared__ float sms[4][16];

    int tq = t0 + l16; if (tq > TT-1) tq = TT-1;
    union { int4 i; unsigned short u[8]; } r0, r1;
    r0.i = *(const int4*)(qB + (size_t)tq*DK + quad*8);
    r1.i = *(const int4*)(qB + (size_t)tq*DK + 32 + quad*8);
    const float* pu = pbu + h*DK + quad*8;
    const float* pv = pbv + h*DK + quad*8;
    union { unsigned short u[8]; bf16x8 v; } qu0, qu1, qv0, qv1;
    #pragma unroll
    for (int i=0;i<8;++i){
        float a0 = b2f(r0.u[i]), a1 = b2f(r1.u[i]);
        qu0.u[i] = f2b(a0 + pu[i]);
        qu1.u[i] = f2b(a1 + pu[32+i]);
        qv0.u[i] = f2b(a0 + pv[i]);
        qv1.u[i] = f2b(a1 + pv[32+i]);
    }

    int Nn = 2*w2 + 1;
    int ntiles = (Nn + 15) >> 4;
    for (int ti = wv; ti < ntiles; ti += 4){
        int n = 127 - w2 + ti*16 + l16; if (n > PEROWS-1) n = PEROWS-1;
        const unsigned short* pr = pB + (size_t)n*DK + quad*8;
        bf16x8 pb0 = *(const bf16x8*)pr;
        bf16x8 pb1 = *(const bf16x8*)(pr + 32);
        floatx4 a = {0.f,0.f,0.f,0.f};
        a = __builtin_amdgcn_mfma_f32_16x16x32_bf16(qv0.v, pb0, a, 0,0,0);
        a = __builtin_amdgcn_mfma_f32_16x16x32_bf16(qv1.v, pb1, a, 0,0,0);
        #pragma unroll
        for (int r=0;r<4;++r) bd[(quad*4+r)*260 + ti*16 + l16] = a[r];
    }
    for (int i = tid; i < 16*328/4; i += 256)
        ((unsigned long long*)pl)[i] = 0ULL;
    __syncthreads();                                     // barrier 1

    int Ns = 2*w2 + 16;
    int stiles = (Ns + 15) >> 4;
    int s_lo = t0 - w2;
    float scv[5][4];
    #pragma unroll
    for (int ii = 0; ii < 5; ++ii){
        int ti = wv + ii*4;
        if (ti < stiles){
            int s = s_lo + ti*16 + l16;
            int sc = s < 0 ? 0 : (s > TT-1 ? TT-1 : s);
            const unsigned short* kr = kB + (size_t)sc*DK + quad*8;
            bf16x8 kb0 = *(const bf16x8*)kr;
            bf16x8 kb1 = *(const bf16x8*)(kr + 32);
            floatx4 a = {0.f,0.f,0.f,0.f};
            a = __builtin_amdgcn_mfma_f32_16x16x32_bf16(qu0.v, kb0, a, 0,0,0);
            a = __builtin_amdgcn_mfma_f32_16x16x32_bf16(qu1.v, kb1, a, 0,0,0);
            #pragma unroll
            for (int r=0;r<4;++r){
                int row = quad*4 + r;
                int nrel = ti*16 + l16 - row;
                bool ok = (nrel >= 0) && (nrel <= 2*w2) && (s >= 0) && (s <= TT-1);
                int idx = row*260 + nrel;
                idx = idx < 0 ? 0 : (idx > 16*260-1 ? 16*260-1 : idx);
                float bdv = bd[idx];
                scv[ii][r] = ok ? (a[r] + bdv) * 0.125f : -1e30f;
            }
        } else {
            #pragma unroll
            for (int r=0;r<4;++r) scv[ii][r] = -1e30f;
        }
    }

    float sm[4] = {0.f,0.f,0.f,0.f};
    #pragma unroll
    for (int ii = 0; ii < 5; ++ii){
        int ti = wv + ii*4;
        if (ti < stiles){
            int pad_base = (t0 - w2) - ((t0 - w2) & ~31);
            #pragma unroll
            for (int r=0;r<4;++r){
                float e = __expf(scv[ii][r]);        // no-max softmax (bounded scores)
                sm[r] += e;
                pl[(quad*4+r)*328 + pad_base + ti*16 + l16] = f2b(e);
            }
        }
    }
    #pragma unroll
    for (int off=1; off<16; off<<=1){
        #pragma unroll
        for (int r=0;r<4;++r) sm[r] += __shfl_xor(sm[r], off);
    }
    if (l16 == 0){
        #pragma unroll
        for (int r=0;r<4;++r) sms[wv][quad*4+r] = sm[r];
    }
    __syncthreads();                                     // barrier 2

    int s_lo2 = t0 - w2;
    int s0a = s_lo2 & ~31;
    int pad_lo = s_lo2 - s0a;
    int ktiles = (pad_lo + Ns + 31) >> 5;

    floatx4 oacc = {0.f,0.f,0.f,0.f};
    for (int kt = 0; kt < ktiles; ++kt){
        bf16x8 pa = *(const bf16x8*)&pl[l16*328 + kt*32 + quad*8];
        int sidx = s0a + kt*32 + quad*8 + 128;
        bf16x8 vb = *(const bf16x8*)(vB + (size_t)(wv*16 + l16)*VTP + sidx);
        oacc = __builtin_amdgcn_mfma_f32_16x16x32_bf16(pa, vb, oacc, 0,0,0);
    }
    #pragma unroll
    for (int r=0;r<4;++r){
        int row = quad*4 + r;
        float sum = sms[0][row] + sms[1][row] + sms[2][row] + sms[3][row];
        float rinv = sum > 0.f ? 1.0f/sum : 0.0f;
        int t = t0 + row;
        if (t <= TT-1)
            out[(((size_t)(b*TT + t))*HH + h)*DK + wv*16 + l16] = f2b(oacc[r] * rinv);
    }
}

// ---------------- launcher (14 dispatches: prep + L0:6 + L1:7) ----------------
extern "C" void kernel_launch(void* const* d_in, const int* in_sizes, int n_in,
                              void* d_out, int out_size, void* d_ws, size_t ws_size,
                              hipStream_t stream){
    const float* x    = (const float*)d_in[0];
    const float* ln1g = (const float*)d_in[2];
    const float* ln1b = (const float*)d_in[3];
    const float* wq   = (const float*)d_in[4];
    const float* bq   = (const float*)d_in[5];
    const float* wk   = (const float*)d_in[6];
    const float* bk   = (const float*)d_in[7];
    const float* wvv  = (const float*)d_in[8];
    const float* bv   = (const float*)d_in[9];
    const float* wo   = (const float*)d_in[10];
    const float* bo   = (const float*)d_in[11];
    const float* wpos = (const float*)d_in[12];
    const float* pbu  = (const float*)d_in[13];
    const float* pbv  = (const float*)d_in[14];
    const float* ln2g = (const float*)d_in[15];
    const float* ln2b = (const float*)d_in[16];
    const float* w1   = (const float*)d_in[17];
    const float* b1   = (const float*)d_in[18];
    const float* w2   = (const float*)d_in[19];
    const float* b2   = (const float*)d_in[20];

    const int NTOK = BB*TT;            // 2000

    float* x_cur = (float*)d_out;      // residual in d_out (fp32)

    // ws layout — total 30,936,576 B
    char* ws = (char*)d_ws;
    unsigned short* qbuf  = (unsigned short*)(ws);              // (b,h,t,d) q / mlp hidden
    unsigned short* kbuf  = (unsigned short*)(ws + 3072000);    // (b,h,t,d)
    unsigned short* vTbuf = (unsigned short*)(ws + 6144000);    // (b,h,d,t+128) 4,030,464 B
    unsigned short* hbuf  = (unsigned short*)(ws + 10174464);   // ln out / attn out
    unsigned short* ppbuf = (unsigned short*)(ws + 13246464);   // (l,h,n,d) 783,360 B
    unsigned short* pebuf = (unsigned short*)(ws + 14029824);   // 391,680 B
    unsigned short* wtbuf = (unsigned short*)(ws + 14421504);   // 14 * 1,179,648 B
    #define WT(t_,l_) (wtbuf + (size_t)((l_)*7 + (t_))*WELEM)

    dim3 blk(256);
    // merged preamble: wconv (z<14) + scale+layer0-ln1 (z=14) + pe (z=15)
    prep_kernel<<<dim3(12,12,16), blk, 0, stream>>>(wq, wk, wvv, wo, wpos, w1, w2,
                                                    wtbuf, x, x_cur, pebuf,
                                                    ln1g, ln1b, hbuf);

    dim3 gBig(32, 12);                 // 64x64 tiles (384 blocks)
    dim3 gAttn(63, BB, HH);

    for (int l = 0; l < LL; ++l){
        long dl = (long)l*DD;
        long pl_ = (long)l*HH*DK;

        // layer-1 ln1 (layer-0's came fused from prep)
        if (l == 1)
            ln_kernel<<<NTOK, blk, 0, stream>>>(x_cur, ln1g + dl, ln1b + dl, hbuf);

        // qkv (layer-0 launch also carries both layers' pos projections: +96 blocks)
        int nqkv = (l == 0) ? 1248 : 1152;
        gemm_qkv_kernel<<<dim3(nqkv), blk, 0, stream>>>(hbuf, WT(0,l), bq + dl, bk + dl, bv + dl,
                                                        qbuf, kbuf, vTbuf,
                                                        pebuf, WT(4,0), ppbuf);

        attn_kernel<<<gAttn, blk, 0, stream>>>(qbuf, kbuf, vTbuf, ppbuf + (size_t)l*PPL,
                                               pbu + pl_, pbv + pl_, hbuf);

        gemm_kernel<2><<<gBig, blk, 0, stream>>>(hbuf, WT(3,l), bo + dl, nullptr, x_cur, NTOK);

        ln_kernel<<<NTOK, blk, 0, stream>>>(x_cur, ln2g + dl, ln2b + dl, hbuf);
        gemm_kernel<1><<<gBig, blk, 0, stream>>>(hbuf, WT(5,l), b1 + dl, qbuf, nullptr, NTOK);
        gemm_kernel<2><<<gBig, blk, 0, stream>>>(qbuf, WT(6,l), b2 + dl, nullptr, x_cur, NTOK);
    }
}